// Round 7
// baseline (28.254 us; speedup 1.0000x reference)
//
#include <hip/hip_runtime.h>

#define N_ATOMS 512
#define N_PAIRS 130816            // 512*511/2
#define BATCH 128

typedef float f32x2 __attribute__((ext_vector_type(2)));

// AU2KCALMOLA / MAX_NRF
constexpr float SCALE = (float)(627.5095 * 0.529177 / 100.0);

// Block blk (0..63) of batch b handles 4 balanced row-pairs:
//   k = 4*blk+m -> rows i1=k (len k) and i2=511-k (len 511-k), 511 pairs each.
// Order: index math -> issue all 8 HBM loads -> stage coords -> barrier ->
// LDS reads -> compute (v_rcp) -> nt stores.  8-deep MLP, loads hidden
// under staging; LDS reads conflict-free (b64 bank-stride 2 / b32 stride 1).
__global__ __launch_bounds__(256) void coords_to_nrf_kernel(
    const float* __restrict__ coords,   // [B, 512, 3]
    const float* __restrict__ atom_nc,  // [B, N_PAIRS]
    float* __restrict__ out)            // [B, N_PAIRS]
{
    __shared__ f32x2 cxy[N_ATOMS];      // 4 KiB
    __shared__ float cz [N_ATOMS];      // 2 KiB

    const int b   = blockIdx.y;
    const int blk = blockIdx.x;         // 0..63
    const int t   = threadIdx.x;

    const float* ab = atom_nc + (size_t)b * N_PAIRS;
    float*       ob = out     + (size_t)b * N_PAIRS;

    // ---- Phase 0: pure-VALU pair indices.
    int pp[8], jj[8];
    bool ff[8];
    #pragma unroll
    for (int m = 0; m < 4; ++m) {
        const int k  = blk * 4 + m;
        const int i1 = k;                   // row length k (empty when k==0)
        const int i2 = 511 - k;             // row length 511-k
        const int base1 = (i1 * (i1 - 1)) / 2;
        const int base2 = (i2 * (i2 - 1)) / 2;
        #pragma unroll
        for (int u = 0; u < 2; ++u) {
            const int r = m * 2 + u;
            // idx 511 clamps to 510: benign duplicate of a neighbor's pair.
            const int idx = (u == 0) ? t : min(256 + t, 510);
            const bool first = idx < i1;
            ff[r] = first;
            jj[r] = first ? idx : idx - i1;
            pp[r] = (first ? base1 : base2) + jj[r];
        }
    }

    // ---- Phase 1: issue ALL streaming loads before any LDS dependency.
    float a[8];
    #pragma unroll
    for (int r = 0; r < 8; ++r) a[r] = ab[pp[r]];

    // ---- Stage coords -> LDS (split xy/z; source is L1/L2-resident).
    {
        const float* cb = coords + (size_t)b * (N_ATOMS * 3);
        #pragma unroll
        for (int s = 0; s < 2; ++s) {
            const int atom = s * 256 + t;
            f32x2 v; v.x = cb[3 * atom]; v.y = cb[3 * atom + 1];
            cxy[atom] = v;
            cz [atom] = cb[3 * atom + 2];
        }
    }
    __syncthreads();

    // ---- Phase 2: hoisted row-atom broadcasts (wave-uniform LDS reads).
    f32x2 ixy1[4], ixy2[4];
    float iz1[4], iz2[4];
    #pragma unroll
    for (int m = 0; m < 4; ++m) {
        const int k = blk * 4 + m;
        ixy1[m] = cxy[k];       iz1[m] = cz[k];
        ixy2[m] = cxy[511 - k]; iz2[m] = cz[511 - k];
    }

    // ---- Phase 3: j-coord LDS reads + compute + nt stores.
    #pragma unroll
    for (int r = 0; r < 8; ++r) {
        const int m = r >> 1;
        const f32x2 jxy = cxy[jj[r]];   // ds_read_b64, bank-stride 2: free
        const float jz  = cz [jj[r]];   // ds_read_b32, bank-stride 1: free
        const f32x2 ixy = ff[r] ? ixy1[m] : ixy2[m];
        const float iz  = ff[r] ? iz1[m]  : iz2[m];
        const float dx = ixy.x - jxy.x;
        const float dy = ixy.y - jxy.y;
        const float dz = iz    - jz;
        const float d2 = dx * dx + dy * dy + dz * dz;
        const float res = a[r] * SCALE * __builtin_amdgcn_rcpf(d2);
        __builtin_nontemporal_store(res, &ob[pp[r]]);
    }
}

extern "C" void kernel_launch(void* const* d_in, const int* in_sizes, int n_in,
                              void* d_out, int out_size, void* d_ws, size_t ws_size,
                              hipStream_t stream) {
    const float* coords  = (const float*)d_in[0];  // [128, 512, 3] f32
    const float* atom_nc = (const float*)d_in[1];  // [128, 130816] f32
    float* out = (float*)d_out;                    // [128, 130816] f32

    dim3 block(256);
    dim3 grid(64, BATCH);                          // 64 blocks x 128 batches
    coords_to_nrf_kernel<<<grid, block, 0, stream>>>(coords, atom_nc, out);
}